// Round 9
// baseline (14.173 us; speedup 1.0000x reference)
//
#include <hip/hip_runtime.h>

#define NB 256
#define NBLOCKS 2048   // 8 blocks/CU on 256 CUs; persistent grid-stride

typedef float vfloat4 __attribute__((ext_vector_type(4)));

// Quad-perm broadcast within each 4-lane group (ds_swizzle, bit15=1 mode).
// PAT = 0x8000 | s | s<<2 | s<<4 | s<<6 broadcasts lane s of the quad.
template <int PAT>
__device__ __forceinline__ float qbcast(float v) {
    return __int_as_float(__builtin_amdgcn_ds_swizzle(__float_as_int(v), PAT));
}

// Closed-form first column of the real Wigner-D blocks, ell = 0..3.
// Persistent grid-stride: waves stay resident (~4 iterations each), letting the
// compiler overlap iteration i+1's loads with iteration i's store drain.
// Each 4-lane quad owns one rotation per iteration; lane q loads m[q], m[q+4];
// quad-perm swizzles distribute {a,b,d,e,g,h}; lane q stores float4 quarter q.
// NT store is load-bearing (R5 vs R6 A/B: 13.6 vs 15.0 us): output is written
// once, never re-read -> NT avoids write-allocate/RFO traffic on 32 MB.
__global__ __launch_bounds__(NB, 8) void rot_embed_kernel(const float* __restrict__ R,
                                                          float* __restrict__ out,
                                                          int n) {
    const long long total4 = (long long)n * 4;           // float4 outputs
    const long long stride = (long long)gridDim.x * NB;  // multiple of 4
    const int q = threadIdx.x & 3;                       // invariant under stride

    for (long long i = (long long)blockIdx.x * NB + threadIdx.x;
         i < total4; i += stride) {
        const long long row = i >> 2;

        const float* rp = R + row * 9;
        const float v0 = rp[q];                      // m[q]
        const float v1 = rp[q + 4];                  // m[q+4]

        // Distribute the 6 needed entries of R (cols 0,1) across the quad.
        const float a = qbcast<0x8000>(v0);          // m[0] from lane 0
        const float b = qbcast<0x8055>(v0);          // m[1] from lane 1
        const float d = qbcast<0x80FF>(v0);          // m[3] from lane 3
        const float e = qbcast<0x8000>(v1);          // m[4] from lane 0
        const float g = qbcast<0x80AA>(v1);          // m[6] from lane 2
        const float h = qbcast<0x80FF>(v1);          // m[7] from lane 3

        const float ab = a * b, de = d * e, gh = g * h;
        const float a2 = a * a, b2 = b * b, d2 = d * d;
        const float e2 = e * e, g2 = g * g, h2 = h * h;

        // ell = 2
        const float t4 = a * e + b * d;
        const float t5 = d * h + e * g;
        const float t6 = 0.5773502691896258f * (2.0f * gh - ab - de);
        const float t7 = a * h + b * g;
        const float t8 = ab - de;

        // ell = 3
        const float t9  = 0.25f * (3.0f * a2 * e + 6.0f * ab * d - 3.0f * d2 * e
                                   - 3.0f * b2 * e + e2 * e);
        const float t10 = 1.2247448713915890f * (a * t5 + b * (d * g - e * h));
        const float t11 = 0.1936491673103709f * (4.0f * g2 * e + 8.0f * gh * d - a2 * e
                                                 - 2.0f * ab * d - 3.0f * d2 * e
                                                 - 4.0f * h2 * e + b2 * e + e2 * e);
        const float t12 = 0.1581138830084190f * (6.0f * g2 * h - 3.0f * a2 * h - 6.0f * ab * g
                                                 - 3.0f * d2 * h - 6.0f * de * g - 2.0f * h2 * h
                                                 + 3.0f * b2 * h + 3.0f * e2 * h);
        const float t13 = 0.1936491673103709f * (4.0f * g2 * b + 8.0f * gh * a - 3.0f * a2 * b
                                                 - d2 * b - 2.0f * de * a - 4.0f * h2 * b
                                                 + b2 * b + e2 * b);
        const float t14 = 0.6123724356957945f * (a2 * h + 2.0f * ab * g - d2 * h
                                                 - 2.0f * de * g - b2 * h + e2 * h);
        const float t15 = 0.25f * (3.0f * a2 * b - 3.0f * d2 * b - 6.0f * de * a
                                   - b2 * b + 3.0f * e2 * b);

        // Branchless quarter select (no divergence within the quad).
        const float vx = (q == 0) ? 1.0f : (q == 1) ? t4  : (q == 2) ? t8  : t12;
        const float vy = (q == 0) ? e    : (q == 1) ? t5  : (q == 2) ? t9  : t13;
        const float vz = (q == 0) ? h    : (q == 1) ? t6  : (q == 2) ? t10 : t14;
        const float vw = (q == 0) ? b    : (q == 1) ? t7  : (q == 2) ? t11 : t15;

        vfloat4 v = {vx, vy, vz, vw};
        __builtin_nontemporal_store(v, (vfloat4*)out + i);   // contiguous per wave
    }
}

extern "C" void kernel_launch(void* const* d_in, const int* in_sizes, int n_in,
                              void* d_out, int out_size, void* d_ws, size_t ws_size,
                              hipStream_t stream) {
    const float* R = (const float*)d_in[0];
    float* out = (float*)d_out;
    const int n = in_sizes[0] / 9;                       // 500000 rotation matrices
    rot_embed_kernel<<<NBLOCKS, NB, 0, stream>>>(R, out, n);
}

// Round 10
// 13.503 us; speedup vs baseline: 1.0496x; 1.0496x over previous
//
#include <hip/hip_runtime.h>

#define NB 256

typedef float vfloat4 __attribute__((ext_vector_type(4)));

// Quad-perm broadcast within each 4-lane group (ds_swizzle, bit15=1 mode).
// PAT = 0x8000 | s | s<<2 | s<<4 | s<<6 broadcasts lane s of the quad.
template <int PAT>
__device__ __forceinline__ float qbcast(float v) {
    return __int_as_float(__builtin_amdgcn_ds_swizzle(__float_as_int(v), PAT));
}

// Closed-form first column of the real Wigner-D blocks, ell = 0..3.
// Best variant (R5, 13.64 us): one thread = one output float4; no LDS tile, no
// barrier, no grid-stride. Each 4-lane quad owns one rotation; lane q loads
// m[q] and m[q+4] (coalesced dwords), quad-perm swizzles distribute
// {a,b,d,e,g,h}; lane q stores float4 quarter q -> contiguous NT dwordx4.
// A/B history: NT store -1.4us (R5 vs R6); NB=1024 neutral (R8); persistent
// grid-stride neutral (R9). Residual ~6us over the 7.6us traffic floor is
// fixed launch/ramp overhead, invariant under all structural changes.
__global__ __launch_bounds__(NB) void rot_embed_kernel(const float* __restrict__ R,
                                                       float* __restrict__ out,
                                                       int n) {
    const long long tid = (long long)blockIdx.x * NB + threadIdx.x;
    const long long row = tid >> 2;              // rotation index
    if (row >= n) return;
    const int q = threadIdx.x & 3;               // quarter owned by this lane

    const float* rp = R + row * 9;
    const float v0 = rp[q];                      // m[q]
    const float v1 = rp[q + 4];                  // m[q+4]

    // Distribute the 6 needed entries of R (cols 0,1) across the quad.
    const float a = qbcast<0x8000>(v0);          // m[0] from lane 0
    const float b = qbcast<0x8055>(v0);          // m[1] from lane 1
    const float d = qbcast<0x80FF>(v0);          // m[3] from lane 3
    const float e = qbcast<0x8000>(v1);          // m[4] from lane 0
    const float g = qbcast<0x80AA>(v1);          // m[6] from lane 2
    const float h = qbcast<0x80FF>(v1);          // m[7] from lane 3

    const float ab = a * b, de = d * e, gh = g * h;
    const float a2 = a * a, b2 = b * b, d2 = d * d;
    const float e2 = e * e, g2 = g * g, h2 = h * h;

    // ell = 2
    const float t4 = a * e + b * d;
    const float t5 = d * h + e * g;
    const float t6 = 0.5773502691896258f * (2.0f * gh - ab - de);
    const float t7 = a * h + b * g;
    const float t8 = ab - de;

    // ell = 3
    const float t9  = 0.25f * (3.0f * a2 * e + 6.0f * ab * d - 3.0f * d2 * e
                               - 3.0f * b2 * e + e2 * e);
    const float t10 = 1.2247448713915890f * (a * t5 + b * (d * g - e * h));
    const float t11 = 0.1936491673103709f * (4.0f * g2 * e + 8.0f * gh * d - a2 * e
                                             - 2.0f * ab * d - 3.0f * d2 * e
                                             - 4.0f * h2 * e + b2 * e + e2 * e);
    const float t12 = 0.1581138830084190f * (6.0f * g2 * h - 3.0f * a2 * h - 6.0f * ab * g
                                             - 3.0f * d2 * h - 6.0f * de * g - 2.0f * h2 * h
                                             + 3.0f * b2 * h + 3.0f * e2 * h);
    const float t13 = 0.1936491673103709f * (4.0f * g2 * b + 8.0f * gh * a - 3.0f * a2 * b
                                             - d2 * b - 2.0f * de * a - 4.0f * h2 * b
                                             + b2 * b + e2 * b);
    const float t14 = 0.6123724356957945f * (a2 * h + 2.0f * ab * g - d2 * h
                                             - 2.0f * de * g - b2 * h + e2 * h);
    const float t15 = 0.25f * (3.0f * a2 * b - 3.0f * d2 * b - 6.0f * de * a
                               - b2 * b + 3.0f * e2 * b);

    // Branchless quarter select (no divergence within the quad).
    const float vx = (q == 0) ? 1.0f : (q == 1) ? t4  : (q == 2) ? t8  : t12;
    const float vy = (q == 0) ? e    : (q == 1) ? t5  : (q == 2) ? t9  : t13;
    const float vz = (q == 0) ? h    : (q == 1) ? t6  : (q == 2) ? t10 : t14;
    const float vw = (q == 0) ? b    : (q == 1) ? t7  : (q == 2) ? t11 : t15;

    vfloat4 v = {vx, vy, vz, vw};
    __builtin_nontemporal_store(v, (vfloat4*)out + tid);   // addr = tid*16B, contiguous
}

extern "C" void kernel_launch(void* const* d_in, const int* in_sizes, int n_in,
                              void* d_out, int out_size, void* d_ws, size_t ws_size,
                              hipStream_t stream) {
    const float* R = (const float*)d_in[0];
    float* out = (float*)d_out;
    const int n = in_sizes[0] / 9;                       // 500000 rotation matrices
    const long long threads = (long long)n * 4;          // one float4 per thread
    const int blocks = (int)((threads + NB - 1) / NB);   // 7813 blocks
    rot_embed_kernel<<<blocks, NB, 0, stream>>>(R, out, n);
}